// Round 4
// baseline (406.533 us; speedup 1.0000x reference)
//
#include <hip/hip_runtime.h>
#include <stdint.h>

typedef unsigned short u16;
typedef __attribute__((ext_vector_type(8))) short short8;
typedef __attribute__((ext_vector_type(4))) float f32x4;

#define NTRACE 4096
#define TLEN   64
#define ISZ    64
#define HSZ    128
#define NBLK   (NTRACE / 4)

__device__ __forceinline__ float bf2f(u16 u) {
  union { uint32_t i; float f; } v; v.i = ((uint32_t)u) << 16; return v.f;
}
__device__ __forceinline__ u16 f2bf(float f) {
  union { float f; uint32_t i; } v; v.f = f;
  uint32_t r = v.i + 0x7fffu + ((v.i >> 16) & 1u);
  return (u16)(r >> 16);
}
__device__ __forceinline__ float sigm(float x) {
  return __builtin_amdgcn_rcpf(1.0f + __expf(-x));
}
__device__ __forceinline__ float tanh_(float x) {
  return 1.0f - 2.0f * __builtin_amdgcn_rcpf(__expf(2.0f * x) + 1.0f);
}
// Load 8 consecutive f32 -> bf16 fragment (used only in k_prep-free paths: emb)
__device__ __forceinline__ short8 load8f(const float* __restrict__ p) {
  f32x4 a = *(const f32x4*)(p);
  f32x4 b = *(const f32x4*)(p + 4);
  short8 r;
  r[0] = (short)f2bf(a[0]); r[1] = (short)f2bf(a[1]);
  r[2] = (short)f2bf(a[2]); r[3] = (short)f2bf(a[3]);
  r[4] = (short)f2bf(b[0]); r[5] = (short)f2bf(b[1]);
  r[6] = (short)f2bf(b[2]); r[7] = (short)f2bf(b[3]);
  return r;
}

// ---------------------------------------------------------------------------
// k_prep: one-time f32->bf16 weight conversion + bias sums into workspace.
// ---------------------------------------------------------------------------
__global__ __launch_bounds__(256) void k_prep(
    const float* __restrict__ W1, const float* __restrict__ W2,
    const float* __restrict__ Wp1,
    const float* __restrict__ b_ih1, const float* __restrict__ b_hh1,
    const float* __restrict__ b_ih2, const float* __restrict__ b_hh2,
    u16* __restrict__ w1b, u16* __restrict__ w2b, u16* __restrict__ wp1b,
    float* __restrict__ bs1, float* __restrict__ bs2)
{
  const int i = blockIdx.x * 256 + threadIdx.x;   // grid: 256 blocks = 65536
  if (i < 512 * 64)  w1b[i]  = f2bf(W1[i]);
  if (i < 512 * 128) w2b[i]  = f2bf(W2[i]);
  if (i < 64 * 128)  wp1b[i] = f2bf(Wp1[i]);
  if (i < 512) { bs1[i] = b_ih1[i] + b_hh1[i]; bs2[i] = b_ih2[i] + b_hh2[i]; }
}

// ---------------------------------------------------------------------------
// k_fused: one wave per trace, 4 traces per block. hbuf (64 KB) holds the
// per-wave token x h tile (bf16), reused h1 -> h2, XOR-chunk-swizzled:
// element (token,h) lives at chunk ((h>>3) ^ (token&15)), breaking the
// row-stride-128 16-way bank aliasing (reads/writes now at the LDS floor).
// Dead token groups (>= len, wave-uniform) are skipped entirely.
// Mid-kernel barriers replaced by wave-local lgkmcnt fences (hbuf regions
// are wave-private); only the final trace-emb staging uses __syncthreads.
// ---------------------------------------------------------------------------
__global__ __launch_bounds__(256) void k_fused(
    const float* __restrict__ emb,
    const u16* __restrict__ w1b, const float* __restrict__ bs1,
    const u16* __restrict__ w2b, const float* __restrict__ bs2,
    const u16* __restrict__ wp1b,
    const float* __restrict__ bp1v, const float* __restrict__ Wp2,
    const float* __restrict__ bp2v,
    const int* __restrict__ traces, const int* __restrict__ lengths,
    float* __restrict__ partials)
{
  __shared__ u16 hbuf[4][TLEN][HSZ];   // 64 KB exactly (per-WG LDS limit safe)

  const int lane = threadIdx.x & 63;
  const int w    = threadIdx.x >> 6;
  const int col  = lane & 15;
  const int q    = lane >> 4;
  const int t    = blockIdx.x * 4 + w;
  const int len  = lengths[t];
  const int ngrp = (len + 15) >> 4;    // wave-uniform active 16-token groups

  const f32x4 z = {0.f, 0.f, 0.f, 0.f};

  // ---- x fragments (B-operand of lstm1), active groups only
  short8 xf[4][2];
#pragma unroll
  for (int g = 0; g < 4; ++g) {
    if (g < ngrp) {
      const int tok = traces[t * TLEN + g * 16 + col];
      const float* xr = emb + (size_t)tok * ISZ + q * 8;
      xf[g][0] = load8f(xr);
      xf[g][1] = load8f(xr + 32);
    }
  }

  // ---- LSTM layer 1 (K=64, 2 k-steps); gate rows i@0, g@256, o@384
#pragma unroll
  for (int mt = 0; mt < 8; ++mt) {
    f32x4 accI[4], accC[4], accO[4];
#pragma unroll
    for (int g = 0; g < 4; ++g)
      if (g < ngrp) { accI[g] = z; accC[g] = z; accO[g] = z; }
#pragma unroll
    for (int ks = 0; ks < 2; ++ks) {
      const u16* wb = w1b + ks * 32 + q * 8;
      short8 fI = *(const short8*)(wb + (size_t)(mt * 16 + col) * ISZ);
      short8 fC = *(const short8*)(wb + (size_t)(256 + mt * 16 + col) * ISZ);
      short8 fO = *(const short8*)(wb + (size_t)(384 + mt * 16 + col) * ISZ);
#pragma unroll
      for (int g = 0; g < 4; ++g) {
        if (g < ngrp) {
          accI[g] = __builtin_amdgcn_mfma_f32_16x16x32_bf16(fI, xf[g][ks], accI[g], 0, 0, 0);
          accC[g] = __builtin_amdgcn_mfma_f32_16x16x32_bf16(fC, xf[g][ks], accC[g], 0, 0, 0);
          accO[g] = __builtin_amdgcn_mfma_f32_16x16x32_bf16(fO, xf[g][ks], accO[g], 0, 0, 0);
        }
      }
    }
    float bI[4], bC[4], bO[4];
#pragma unroll
    for (int r = 0; r < 4; ++r) {
      const int h = mt * 16 + q * 4 + r;
      bI[r] = bs1[h]; bC[r] = bs1[256 + h]; bO[r] = bs1[384 + h];
    }
    // swizzled write: chunk = mt*2 + (q>>1), within-chunk (q&1)*4
    const int wchunk = ((mt * 2 + (q >> 1)) ^ col) * 8 + (q & 1) * 4;
#pragma unroll
    for (int g = 0; g < 4; ++g) {
      if (g < ngrp) {
        u16 hv[4];
#pragma unroll
        for (int r = 0; r < 4; ++r) {
          float c = sigm(accI[g][r] + bI[r]) * tanh_(accC[g][r] + bC[r]);
          hv[r] = f2bf(sigm(accO[g][r] + bO[r]) * tanh_(c));
        }
        uint2 pk;
        pk.x = (uint32_t)hv[0] | ((uint32_t)hv[1] << 16);
        pk.y = (uint32_t)hv[2] | ((uint32_t)hv[3] << 16);
        *(uint2*)&hbuf[w][g * 16 + col][wchunk] = pk;
      }
    }
  }
  asm volatile("s_waitcnt lgkmcnt(0)" ::: "memory");  // wave-private hbuf

  // ---- load h1 fragments (B-operand of lstm2), swizzled chunks
  short8 hf[4][4];
#pragma unroll
  for (int g = 0; g < 4; ++g)
#pragma unroll
    for (int ks = 0; ks < 4; ++ks)
      if (g < ngrp)
        hf[g][ks] = *(const short8*)&hbuf[w][g * 16 + col][((ks * 4 + q) ^ col) * 8];
  asm volatile("s_waitcnt lgkmcnt(0)" ::: "memory");  // reads done before overwrite

  // ---- LSTM layer 2 (K=128, 4 k-steps)
#pragma unroll
  for (int mt = 0; mt < 8; ++mt) {
    f32x4 accI[4], accC[4], accO[4];
#pragma unroll
    for (int g = 0; g < 4; ++g)
      if (g < ngrp) { accI[g] = z; accC[g] = z; accO[g] = z; }
#pragma unroll
    for (int ks = 0; ks < 4; ++ks) {
      const u16* wb = w2b + ks * 32 + q * 8;
      short8 fI = *(const short8*)(wb + (size_t)(mt * 16 + col) * HSZ);
      short8 fC = *(const short8*)(wb + (size_t)(256 + mt * 16 + col) * HSZ);
      short8 fO = *(const short8*)(wb + (size_t)(384 + mt * 16 + col) * HSZ);
#pragma unroll
      for (int g = 0; g < 4; ++g) {
        if (g < ngrp) {
          accI[g] = __builtin_amdgcn_mfma_f32_16x16x32_bf16(fI, hf[g][ks], accI[g], 0, 0, 0);
          accC[g] = __builtin_amdgcn_mfma_f32_16x16x32_bf16(fC, hf[g][ks], accC[g], 0, 0, 0);
          accO[g] = __builtin_amdgcn_mfma_f32_16x16x32_bf16(fO, hf[g][ks], accO[g], 0, 0, 0);
        }
      }
    }
    float bI[4], bC[4], bO[4];
#pragma unroll
    for (int r = 0; r < 4; ++r) {
      const int h = mt * 16 + q * 4 + r;
      bI[r] = bs2[h]; bC[r] = bs2[256 + h]; bO[r] = bs2[384 + h];
    }
    const int wchunk = ((mt * 2 + (q >> 1)) ^ col) * 8 + (q & 1) * 4;
#pragma unroll
    for (int g = 0; g < 4; ++g) {
      if (g < ngrp) {
        u16 hv[4];
#pragma unroll
        for (int r = 0; r < 4; ++r) {
          float c = sigm(accI[g][r] + bI[r]) * tanh_(accC[g][r] + bC[r]);
          hv[r] = f2bf(sigm(accO[g][r] + bO[r]) * tanh_(c));
        }
        uint2 pk;
        pk.x = (uint32_t)hv[0] | ((uint32_t)hv[1] << 16);
        pk.y = (uint32_t)hv[2] | ((uint32_t)hv[3] << 16);
        *(uint2*)&hbuf[w][g * 16 + col][wchunk] = pk;
      }
    }
  }
  asm volatile("s_waitcnt lgkmcnt(0)" ::: "memory");

  // ---- reload fragments: now h2
#pragma unroll
  for (int g = 0; g < 4; ++g)
#pragma unroll
    for (int ks = 0; ks < 4; ++ks)
      if (g < ngrp)
        hf[g][ks] = *(const short8*)&hbuf[w][g * 16 + col][((ks * 4 + q) ^ col) * 8];

  // ---- attention-MLP energy: p = relu(h2 @ Wp1.T + bp1); e = p @ Wp2 + bp2
  float ep[4] = {0.f, 0.f, 0.f, 0.f};
#pragma unroll
  for (int mt = 0; mt < 4; ++mt) {
    f32x4 acc[4];
#pragma unroll
    for (int g = 0; g < 4; ++g) acc[g] = z;
#pragma unroll
    for (int ks = 0; ks < 4; ++ks) {
      short8 fA = *(const short8*)(wp1b + (size_t)(mt * 16 + col) * HSZ + ks * 32 + q * 8);
#pragma unroll
      for (int g = 0; g < 4; ++g)
        if (g < ngrp)
          acc[g] = __builtin_amdgcn_mfma_f32_16x16x32_bf16(fA, hf[g][ks], acc[g], 0, 0, 0);
    }
#pragma unroll
    for (int r = 0; r < 4; ++r) {
      const int hp = mt * 16 + q * 4 + r;
      const float b1 = bp1v[hp];
      const float w2 = Wp2[hp];
#pragma unroll
      for (int g = 0; g < 4; ++g)
        ep[g] += fmaxf(acc[g][r] + b1, 0.f) * w2;
    }
  }
#pragma unroll
  for (int g = 0; g < 4; ++g) {
    ep[g] += __shfl_xor(ep[g], 16);
    ep[g] += __shfl_xor(ep[g], 32);
  }
  const float bp2f = bp2v[0];

  // ---- masked softmax over 64 positions (token l = g*16 + col)
  float e[4]; bool val[4];
  float m = -3.0e38f;
#pragma unroll
  for (int g = 0; g < 4; ++g) {
    const int l = g * 16 + col;
    val[g] = l < len;
    e[g] = ep[g] + bp2f;
    m = fmaxf(m, val[g] ? e[g] : -3.0e38f);
  }
  m = fmaxf(m, __shfl_xor(m, 1));
  m = fmaxf(m, __shfl_xor(m, 2));
  m = fmaxf(m, __shfl_xor(m, 4));
  m = fmaxf(m, __shfl_xor(m, 8));
  float wgt[4], s = 0.f;
#pragma unroll
  for (int g = 0; g < 4; ++g) {
    wgt[g] = val[g] ? __expf(e[g] - m) : 0.f;
    s += wgt[g];
  }
  s += __shfl_xor(s, 1);
  s += __shfl_xor(s, 2);
  s += __shfl_xor(s, 4);
  s += __shfl_xor(s, 8);
  const float inv = __builtin_amdgcn_rcpf(s);
#pragma unroll
  for (int g = 0; g < 4; ++g) wgt[g] *= inv;

  // ---- weighted sum: te[h] = sum_l wgt[l] * h2[l][h]
  // lane handles h = 4*(lane&31)..+3; positions l = 2*i + (lane>>5).
  const int half = lane >> 5;
  const int hb   = (lane & 31) * 4;
  const int rchunk = ((hb >> 3) /* ^ (l&15) applied per-l */) ;
  float a4[4] = {0.f, 0.f, 0.f, 0.f};
#pragma unroll
  for (int g = 0; g < 4; ++g) {
    if (g * 16 < len) {
#pragma unroll
      for (int i = 0; i < 8; ++i) {
        const int l = g * 16 + 2 * i + half;
        const float wl = __shfl(wgt[g], l & 15, 64);
        const int sw = ((rchunk ^ (l & 15)) * 8) + (hb & 7);
        const uint2 hv = *(const uint2*)&hbuf[w][l][sw];
        a4[0] += wl * bf2f((u16)(hv.x & 0xffffu));
        a4[1] += wl * bf2f((u16)(hv.x >> 16));
        a4[2] += wl * bf2f((u16)(hv.y & 0xffffu));
        a4[3] += wl * bf2f((u16)(hv.y >> 16));
      }
    }
  }
#pragma unroll
  for (int k = 0; k < 4; ++k) a4[k] += __shfl_xor(a4[k], 32);

  __syncthreads();                    // everyone done with hbuf
  float* teb = (float*)hbuf;          // overlay: 4 waves x 128 floats = 2 KB
  if (half == 0) {
#pragma unroll
    for (int k = 0; k < 4; ++k) teb[w * HSZ + hb + k] = a4[k];
  }
  __syncthreads();

  // ---- per-block partial (plain store; summed by k_reduce)
  if (threadIdx.x < HSZ) {
    const int h = threadIdx.x;
    partials[(size_t)blockIdx.x * HSZ + h] =
        teb[h] + teb[HSZ + h] + teb[2 * HSZ + h] + teb[3 * HSZ + h];
  }
}

// ---------------------------------------------------------------------------
// k_reduce: fin[h] = sum over 1024 block partials
// ---------------------------------------------------------------------------
__global__ __launch_bounds__(256) void k_reduce(
    const float* __restrict__ partials, float* __restrict__ fin)
{
  const int h = blockIdx.x;
  float s = 0.f;
  for (int b = threadIdx.x; b < NBLK; b += 256) s += partials[(size_t)b * HSZ + h];
#pragma unroll
  for (int off = 32; off >= 1; off >>= 1) s += __shfl_xor(s, off);
  __shared__ float part[4];
  if ((threadIdx.x & 63) == 0) part[threadIdx.x >> 6] = s;
  __syncthreads();
  if (threadIdx.x == 0) fin[h] = part[0] + part[1] + part[2] + part[3];
}

// out = final @ W_out.T + b_out   (128x128, one block, FP32)
__global__ __launch_bounds__(128) void k_out(
    const float* __restrict__ fin, const float* __restrict__ W_out,
    const float* __restrict__ b_out, float* __restrict__ out)
{
  const int o = threadIdx.x;
  __shared__ float fs[HSZ];
  fs[o] = fin[o];
  __syncthreads();
  float acc = b_out[o];
  const float* wr = W_out + (size_t)o * HSZ;
#pragma unroll
  for (int h = 0; h < HSZ; ++h) acc += wr[h] * fs[h];
  out[o] = acc;
}

extern "C" void kernel_launch(void* const* d_in, const int* in_sizes, int n_in,
                              void* d_out, int out_size, void* d_ws, size_t ws_size,
                              hipStream_t stream)
{
  const float* emb   = (const float*)d_in[0];
  const float* W_ih1 = (const float*)d_in[1];
  // d_in[2] = W_hh1: unused (h0 = 0)
  const float* b_ih1 = (const float*)d_in[3];
  const float* b_hh1 = (const float*)d_in[4];
  const float* W_ih2 = (const float*)d_in[5];
  // d_in[6] = W_hh2: unused
  const float* b_ih2 = (const float*)d_in[7];
  const float* b_hh2 = (const float*)d_in[8];
  const float* Wp1   = (const float*)d_in[9];
  const float* bp1   = (const float*)d_in[10];
  const float* Wp2   = (const float*)d_in[11];
  const float* bp2   = (const float*)d_in[12];
  const float* W_out = (const float*)d_in[13];
  const float* b_out = (const float*)d_in[14];
  const int* traces  = (const int*)d_in[15];
  const int* lengths = (const int*)d_in[16];

  char* ws = (char*)d_ws;
  u16*   w1b      = (u16*)(ws);                  // 512*64*2  = 65536 B
  u16*   w2b      = (u16*)(ws + 65536);          // 512*128*2 = 131072 B
  u16*   wp1b     = (u16*)(ws + 196608);         // 64*128*2  = 16384 B
  float* bs1      = (float*)(ws + 212992);       // 512*4 = 2048 B
  float* bs2      = (float*)(ws + 215040);       // 2048 B
  float* fin      = (float*)(ws + 217088);       // 512 B
  float* partials = (float*)(ws + 217600);       // 1024*128*4 = 524288 B

  k_prep<<<256, 256, 0, stream>>>(W_ih1, W_ih2, Wp1, b_ih1, b_hh1, b_ih2, b_hh2,
                                  w1b, w2b, wp1b, bs1, bs2);
  k_fused<<<NBLK, 256, 0, stream>>>(emb, w1b, bs1, w2b, bs2, wp1b,
                                    bp1, Wp2, bp2, traces, lengths, partials);
  k_reduce<<<HSZ, 256, 0, stream>>>(partials, fin);
  k_out<<<1, 128, 0, stream>>>(fin, W_out, b_out, (float*)d_out);
}

// Round 5
// 208.618 us; speedup vs baseline: 1.9487x; 1.9487x over previous
//
#include <hip/hip_runtime.h>
#include <stdint.h>

typedef unsigned short u16;
typedef __attribute__((ext_vector_type(8))) short short8;
typedef __attribute__((ext_vector_type(4))) float f32x4;

#define NTRACE 4096
#define TLEN   64
#define ISZ    64
#define HSZ    128
#define NBLK   NTRACE            // 1 trace per 64-thread block

__device__ __forceinline__ float bf2f(u16 u) {
  union { uint32_t i; float f; } v; v.i = ((uint32_t)u) << 16; return v.f;
}
__device__ __forceinline__ u16 f2bf(float f) {
  union { float f; uint32_t i; } v; v.f = f;
  uint32_t r = v.i + 0x7fffu + ((v.i >> 16) & 1u);
  return (u16)(r >> 16);
}
// tanh(gc) * sigm(go) with 2 exp + 1 rcp (exact):
// (e^{2gc}-1) / ((e^{2gc}+1) * (1+e^{-go}))
__device__ __forceinline__ float gate_pair(float go, float gc) {
  float E = __expf(2.0f * gc);
  float B = __expf(-go);
  return (E - 1.0f) * __builtin_amdgcn_rcpf((E + 1.0f) * (1.0f + B));
}
__device__ __forceinline__ short8 load8f(const float* __restrict__ p) {
  f32x4 a = *(const f32x4*)(p);
  f32x4 b = *(const f32x4*)(p + 4);
  short8 r;
  r[0] = (short)f2bf(a[0]); r[1] = (short)f2bf(a[1]);
  r[2] = (short)f2bf(a[2]); r[3] = (short)f2bf(a[3]);
  r[4] = (short)f2bf(b[0]); r[5] = (short)f2bf(b[1]);
  r[6] = (short)f2bf(b[2]); r[7] = (short)f2bf(b[3]);
  return r;
}

// ---------------------------------------------------------------------------
// k_prep: one-time f32->bf16 weight conversion + bias sums into workspace.
// ---------------------------------------------------------------------------
__global__ __launch_bounds__(256) void k_prep(
    const float* __restrict__ W1, const float* __restrict__ W2,
    const float* __restrict__ Wp1,
    const float* __restrict__ b_ih1, const float* __restrict__ b_hh1,
    const float* __restrict__ b_ih2, const float* __restrict__ b_hh2,
    u16* __restrict__ w1b, u16* __restrict__ w2b, u16* __restrict__ wp1b,
    float* __restrict__ bs1, float* __restrict__ bs2)
{
  const int i = blockIdx.x * 256 + threadIdx.x;   // 256 blocks = 65536 threads
  if (i < 512 * 64)  w1b[i]  = f2bf(W1[i]);
  if (i < 512 * 128) w2b[i]  = f2bf(W2[i]);
  if (i < 64 * 128)  wp1b[i] = f2bf(Wp1[i]);
  if (i < 512) { bs1[i] = b_ih1[i] + b_hh1[i]; bs2[i] = b_ih2[i] + b_hh2[i]; }
}

// ---------------------------------------------------------------------------
// trace_body<NG>: one wave, one trace, NG = ceil(len/16) active token groups.
// Branch-free per instantiation (wave-uniform dispatch keeps VGPR at the
// NG=4 level, ~R3's 112 — R4's per-g predication doubled it to 224).
// hbuf XOR-chunk swizzle: (token,h) -> column ((h>>3)^(token&15))*8 + (h&7).
// ---------------------------------------------------------------------------
template<int NG>
__device__ __forceinline__ void trace_body(
    u16* __restrict__ hbuf,            // [TLEN][HSZ] flat, wave-private
    float* __restrict__ wbuf,          // [TLEN] softmax weights
    const float* __restrict__ emb,
    const u16* __restrict__ w1b, const float* __restrict__ bs1,
    const u16* __restrict__ w2b, const float* __restrict__ bs2,
    const u16* __restrict__ wp1b,
    const float* __restrict__ bp1v, const float* __restrict__ Wp2,
    const float* __restrict__ bp2v,
    const int* __restrict__ traces,
    float* __restrict__ partials, int t, int len)
{
  const int lane = threadIdx.x & 63;
  const int col  = lane & 15;
  const int q    = lane >> 4;
  const f32x4 z = {0.f, 0.f, 0.f, 0.f};

  // ---- x fragments (B-operand of lstm1)
  short8 xf[NG][2];
#pragma unroll
  for (int g = 0; g < NG; ++g) {
    const int tok = traces[t * TLEN + g * 16 + col];
    const float* xr = emb + (size_t)tok * ISZ + q * 8;
    xf[g][0] = load8f(xr);
    xf[g][1] = load8f(xr + 32);
  }

  // ---- LSTM layer 1 (K=64); gate rows i@0, g@256, o@384
#pragma unroll
  for (int mt = 0; mt < 8; ++mt) {
    f32x4 aI[NG], aC[NG], aO[NG];
#pragma unroll
    for (int g = 0; g < NG; ++g) { aI[g] = z; aC[g] = z; aO[g] = z; }
#pragma unroll
    for (int ks = 0; ks < 2; ++ks) {
      const u16* wb = w1b + ks * 32 + q * 8;
      short8 fI = *(const short8*)(wb + (size_t)(mt * 16 + col) * ISZ);
      short8 fC = *(const short8*)(wb + (size_t)(256 + mt * 16 + col) * ISZ);
      short8 fO = *(const short8*)(wb + (size_t)(384 + mt * 16 + col) * ISZ);
#pragma unroll
      for (int g = 0; g < NG; ++g) {
        aI[g] = __builtin_amdgcn_mfma_f32_16x16x32_bf16(fI, xf[g][ks], aI[g], 0, 0, 0);
        aC[g] = __builtin_amdgcn_mfma_f32_16x16x32_bf16(fC, xf[g][ks], aC[g], 0, 0, 0);
        aO[g] = __builtin_amdgcn_mfma_f32_16x16x32_bf16(fO, xf[g][ks], aO[g], 0, 0, 0);
      }
    }
    float bI[4], bC[4], bO[4];
#pragma unroll
    for (int r = 0; r < 4; ++r) {
      const int h = mt * 16 + q * 4 + r;
      bI[r] = bs1[h]; bC[r] = bs1[256 + h]; bO[r] = bs1[384 + h];
    }
    const int wcol = ((mt * 2 + (q >> 1)) ^ col) * 8 + (q & 1) * 4;
#pragma unroll
    for (int g = 0; g < NG; ++g) {
      u16 hv[4];
#pragma unroll
      for (int r = 0; r < 4; ++r) {
        float c = gate_pair(aI[g][r] + bI[r], aC[g][r] + bC[r]);
        hv[r] = f2bf(gate_pair(aO[g][r] + bO[r], c));
      }
      uint2 pk;
      pk.x = (uint32_t)hv[0] | ((uint32_t)hv[1] << 16);
      pk.y = (uint32_t)hv[2] | ((uint32_t)hv[3] << 16);
      *(uint2*)&hbuf[(g * 16 + col) * HSZ + wcol] = pk;
    }
  }
  asm volatile("s_waitcnt lgkmcnt(0)" ::: "memory");

  // ---- h1 fragments (B-operand of lstm2), swizzled reads
  short8 hf[NG][4];
#pragma unroll
  for (int g = 0; g < NG; ++g)
#pragma unroll
    for (int ks = 0; ks < 4; ++ks)
      hf[g][ks] = *(const short8*)&hbuf[(g * 16 + col) * HSZ + ((ks * 4 + q) ^ col) * 8];
  asm volatile("s_waitcnt lgkmcnt(0)" ::: "memory");

  // ---- LSTM layer 2 (K=128)
#pragma unroll
  for (int mt = 0; mt < 8; ++mt) {
    f32x4 aI[NG], aC[NG], aO[NG];
#pragma unroll
    for (int g = 0; g < NG; ++g) { aI[g] = z; aC[g] = z; aO[g] = z; }
#pragma unroll
    for (int ks = 0; ks < 4; ++ks) {
      const u16* wb = w2b + ks * 32 + q * 8;
      short8 fI = *(const short8*)(wb + (size_t)(mt * 16 + col) * HSZ);
      short8 fC = *(const short8*)(wb + (size_t)(256 + mt * 16 + col) * HSZ);
      short8 fO = *(const short8*)(wb + (size_t)(384 + mt * 16 + col) * HSZ);
#pragma unroll
      for (int g = 0; g < NG; ++g) {
        aI[g] = __builtin_amdgcn_mfma_f32_16x16x32_bf16(fI, hf[g][ks], aI[g], 0, 0, 0);
        aC[g] = __builtin_amdgcn_mfma_f32_16x16x32_bf16(fC, hf[g][ks], aC[g], 0, 0, 0);
        aO[g] = __builtin_amdgcn_mfma_f32_16x16x32_bf16(fO, hf[g][ks], aO[g], 0, 0, 0);
      }
    }
    float bI[4], bC[4], bO[4];
#pragma unroll
    for (int r = 0; r < 4; ++r) {
      const int h = mt * 16 + q * 4 + r;
      bI[r] = bs2[h]; bC[r] = bs2[256 + h]; bO[r] = bs2[384 + h];
    }
    const int wcol = ((mt * 2 + (q >> 1)) ^ col) * 8 + (q & 1) * 4;
#pragma unroll
    for (int g = 0; g < NG; ++g) {
      u16 hv[4];
#pragma unroll
      for (int r = 0; r < 4; ++r) {
        float c = gate_pair(aI[g][r] + bI[r], aC[g][r] + bC[r]);
        hv[r] = f2bf(gate_pair(aO[g][r] + bO[r], c));
      }
      uint2 pk;
      pk.x = (uint32_t)hv[0] | ((uint32_t)hv[1] << 16);
      pk.y = (uint32_t)hv[2] | ((uint32_t)hv[3] << 16);
      *(uint2*)&hbuf[(g * 16 + col) * HSZ + wcol] = pk;
    }
  }
  asm volatile("s_waitcnt lgkmcnt(0)" ::: "memory");

  // ---- reload fragments: now h2
#pragma unroll
  for (int g = 0; g < NG; ++g)
#pragma unroll
    for (int ks = 0; ks < 4; ++ks)
      hf[g][ks] = *(const short8*)&hbuf[(g * 16 + col) * HSZ + ((ks * 4 + q) ^ col) * 8];

  // ---- attention-MLP energy
  float ep[NG];
#pragma unroll
  for (int g = 0; g < NG; ++g) ep[g] = 0.f;
#pragma unroll
  for (int mt = 0; mt < 4; ++mt) {
    f32x4 acc[NG];
#pragma unroll
    for (int g = 0; g < NG; ++g) acc[g] = z;
#pragma unroll
    for (int ks = 0; ks < 4; ++ks) {
      short8 fA = *(const short8*)(wp1b + (size_t)(mt * 16 + col) * HSZ + ks * 32 + q * 8);
#pragma unroll
      for (int g = 0; g < NG; ++g)
        acc[g] = __builtin_amdgcn_mfma_f32_16x16x32_bf16(fA, hf[g][ks], acc[g], 0, 0, 0);
    }
#pragma unroll
    for (int r = 0; r < 4; ++r) {
      const int hp = mt * 16 + q * 4 + r;
      const float b1 = bp1v[hp];
      const float w2 = Wp2[hp];
#pragma unroll
      for (int g = 0; g < NG; ++g)
        ep[g] += fmaxf(acc[g][r] + b1, 0.f) * w2;
    }
  }
#pragma unroll
  for (int g = 0; g < NG; ++g) {
    ep[g] += __shfl_xor(ep[g], 16);
    ep[g] += __shfl_xor(ep[g], 32);
  }
  const float bp2f = bp2v[0];

  // ---- masked softmax (token l = g*16 + col)
  float e[NG]; bool val[NG];
  float m = -3.0e38f;
#pragma unroll
  for (int g = 0; g < NG; ++g) {
    val[g] = (g * 16 + col) < len;
    e[g] = ep[g] + bp2f;
    m = fmaxf(m, val[g] ? e[g] : -3.0e38f);
  }
  m = fmaxf(m, __shfl_xor(m, 1));
  m = fmaxf(m, __shfl_xor(m, 2));
  m = fmaxf(m, __shfl_xor(m, 4));
  m = fmaxf(m, __shfl_xor(m, 8));
  float wgt[NG], s = 0.f;
#pragma unroll
  for (int g = 0; g < NG; ++g) {
    wgt[g] = val[g] ? __expf(e[g] - m) : 0.f;
    s += wgt[g];
  }
  s += __shfl_xor(s, 1);
  s += __shfl_xor(s, 2);
  s += __shfl_xor(s, 4);
  s += __shfl_xor(s, 8);
  const float inv = __builtin_amdgcn_rcpf(s);
  if (q == 0) {
#pragma unroll
    for (int g = 0; g < NG; ++g) wbuf[g * 16 + col] = wgt[g] * inv;
  }
  asm volatile("s_waitcnt lgkmcnt(0)" ::: "memory");

  // ---- weighted sum: te[h] = sum_l w[l] * h2[l][h]
  // lane covers h = 4*(lane&31)..+3; positions l = 2*i + (lane>>5)
  const int half = lane >> 5;
  const int hb   = (lane & 31) * 4;
  const int rchunk = hb >> 3;
  float a4[4] = {0.f, 0.f, 0.f, 0.f};
#pragma unroll
  for (int g = 0; g < NG; ++g) {
#pragma unroll
    for (int i = 0; i < 8; ++i) {
      const int l = g * 16 + 2 * i + half;
      const float wl = wbuf[l];
      const int sw = ((rchunk ^ (l & 15)) * 8) + (hb & 7);
      const uint2 hv = *(const uint2*)&hbuf[l * HSZ + sw];
      a4[0] += wl * bf2f((u16)(hv.x & 0xffffu));
      a4[1] += wl * bf2f((u16)(hv.x >> 16));
      a4[2] += wl * bf2f((u16)(hv.y & 0xffffu));
      a4[3] += wl * bf2f((u16)(hv.y >> 16));
    }
  }
#pragma unroll
  for (int k = 0; k < 4; ++k) a4[k] += __shfl_xor(a4[k], 32);

  if (half == 0) {
    f32x4 st = {a4[0], a4[1], a4[2], a4[3]};
    *(f32x4*)&partials[(size_t)t * HSZ + hb] = st;
  }
}

// ---------------------------------------------------------------------------
// k_fused: 1 wave per block, 1 trace per block; uniform template dispatch.
// LDS = 16.6 KB -> ~9 blocks/CU.
// ---------------------------------------------------------------------------
__global__ __launch_bounds__(64) void k_fused(
    const float* __restrict__ emb,
    const u16* __restrict__ w1b, const float* __restrict__ bs1,
    const u16* __restrict__ w2b, const float* __restrict__ bs2,
    const u16* __restrict__ wp1b,
    const float* __restrict__ bp1v, const float* __restrict__ Wp2,
    const float* __restrict__ bp2v,
    const int* __restrict__ traces, const int* __restrict__ lengths,
    float* __restrict__ partials)
{
  __shared__ u16 hbuf[TLEN * HSZ];   // 16 KB
  __shared__ float wbuf[TLEN];       // 256 B
  const int t = blockIdx.x;
  const int len = lengths[t];
  const int ngrp = (len + 15) >> 4;
  switch (ngrp) {
    case 1: trace_body<1>(hbuf, wbuf, emb, w1b, bs1, w2b, bs2, wp1b,
                          bp1v, Wp2, bp2v, traces, partials, t, len); break;
    case 2: trace_body<2>(hbuf, wbuf, emb, w1b, bs1, w2b, bs2, wp1b,
                          bp1v, Wp2, bp2v, traces, partials, t, len); break;
    case 3: trace_body<3>(hbuf, wbuf, emb, w1b, bs1, w2b, bs2, wp1b,
                          bp1v, Wp2, bp2v, traces, partials, t, len); break;
    default: trace_body<4>(hbuf, wbuf, emb, w1b, bs1, w2b, bs2, wp1b,
                           bp1v, Wp2, bp2v, traces, partials, t, len); break;
  }
}

// ---------------------------------------------------------------------------
// k_reduce: fin[h] = sum over 4096 trace partials
// ---------------------------------------------------------------------------
__global__ __launch_bounds__(256) void k_reduce(
    const float* __restrict__ partials, float* __restrict__ fin)
{
  const int h = blockIdx.x;
  float s = 0.f;
  for (int b = threadIdx.x; b < NBLK; b += 256) s += partials[(size_t)b * HSZ + h];
#pragma unroll
  for (int off = 32; off >= 1; off >>= 1) s += __shfl_xor(s, off);
  __shared__ float part[4];
  if ((threadIdx.x & 63) == 0) part[threadIdx.x >> 6] = s;
  __syncthreads();
  if (threadIdx.x == 0) fin[h] = part[0] + part[1] + part[2] + part[3];
}

// out = final @ W_out.T + b_out   (128x128, one block, FP32)
__global__ __launch_bounds__(128) void k_out(
    const float* __restrict__ fin, const float* __restrict__ W_out,
    const float* __restrict__ b_out, float* __restrict__ out)
{
  const int o = threadIdx.x;
  __shared__ float fs[HSZ];
  fs[o] = fin[o];
  __syncthreads();
  float acc = b_out[o];
  const float* wr = W_out + (size_t)o * HSZ;
#pragma unroll
  for (int h = 0; h < HSZ; ++h) acc += wr[h] * fs[h];
  out[o] = acc;
}

extern "C" void kernel_launch(void* const* d_in, const int* in_sizes, int n_in,
                              void* d_out, int out_size, void* d_ws, size_t ws_size,
                              hipStream_t stream)
{
  const float* emb   = (const float*)d_in[0];
  const float* W_ih1 = (const float*)d_in[1];
  // d_in[2] = W_hh1: unused (h0 = 0)
  const float* b_ih1 = (const float*)d_in[3];
  const float* b_hh1 = (const float*)d_in[4];
  const float* W_ih2 = (const float*)d_in[5];
  // d_in[6] = W_hh2: unused
  const float* b_ih2 = (const float*)d_in[7];
  const float* b_hh2 = (const float*)d_in[8];
  const float* Wp1   = (const float*)d_in[9];
  const float* bp1   = (const float*)d_in[10];
  const float* Wp2   = (const float*)d_in[11];
  const float* bp2   = (const float*)d_in[12];
  const float* W_out = (const float*)d_in[13];
  const float* b_out = (const float*)d_in[14];
  const int* traces  = (const int*)d_in[15];
  const int* lengths = (const int*)d_in[16];

  char* ws = (char*)d_ws;
  u16*   w1b      = (u16*)(ws);                  // 512*64*2  = 65536 B
  u16*   w2b      = (u16*)(ws + 65536);          // 512*128*2 = 131072 B
  u16*   wp1b     = (u16*)(ws + 196608);         // 64*128*2  = 16384 B
  float* bs1      = (float*)(ws + 212992);       // 2048 B
  float* bs2      = (float*)(ws + 215040);       // 2048 B
  float* fin      = (float*)(ws + 217088);       // 512 B
  float* partials = (float*)(ws + 217600);       // 4096*128*4 = 2 MiB

  k_prep<<<256, 256, 0, stream>>>(W_ih1, W_ih2, Wp1, b_ih1, b_hh1, b_ih2, b_hh2,
                                  w1b, w2b, wp1b, bs1, bs2);
  k_fused<<<NBLK, 64, 0, stream>>>(emb, w1b, bs1, w2b, bs2, wp1b,
                                   bp1, Wp2, bp2, traces, lengths, partials);
  k_reduce<<<HSZ, 256, 0, stream>>>(partials, fin);
  k_out<<<1, 128, 0, stream>>>(fin, W_out, b_out, (float*)d_out);
}